// Round 3
// baseline (285.429 us; speedup 1.0000x reference)
//
#include <hip/hip_runtime.h>
#include <cstdint>
#include <cstddef>

// Problem: B=128, S=512, H=512
//   context[b,h] = sum_s softmax_s( sum_k tanh(u[b,s,k]) Ve[k] ) * h[b,s,h]
//   u = h@U1a^T + x@U2^T + (h_last@U1b^T broadcast over s)
// R3: 2-phase double-buffered GEMM (T3 minimal recipe + counted-vmcnt barrier).
//   BM=128 BN=128 BK=64, 4 waves, wave tile 64x64.
//   A: global->reg (2 tiles ahead) ->cvt fp16-> LDS (write-late, XOR-swizzled).
//   B: global_load_lds from pre-swizzled fp16 tile images (1 tile ahead).

typedef _Float16 h8 __attribute__((ext_vector_type(8)));
typedef float    f4 __attribute__((ext_vector_type(4)));

#define GLOAD16(g, l)                                                          \
  __builtin_amdgcn_global_load_lds(                                            \
      (const __attribute__((address_space(1))) void*)(g),                      \
      (__attribute__((address_space(3))) void*)(l), 16, 0, 0)

// Counted barrier: drain oldest loads down to N, publish LDS, sync.
// N=8 keeps the 8 A-register loads (private) in flight across the barrier.
#define PIPE_BARRIER(N)                                                        \
  do {                                                                         \
    asm volatile("s_waitcnt vmcnt(" #N ") lgkmcnt(0)\n\ts_barrier" ::: "memory"); \
    __builtin_amdgcn_sched_barrier(0);                                         \
  } while (0)

// ---------------------------------------------------------------------------
// Setup: Bws = 64 tile images (nt 0..3, kt 0..15), each 128 rows x 8 slots x 16B,
// swizzle baked: image(r, s) = fp16 U[nt*128+r][kt*64 + ((s^(r&7))<<3) .. +8]
// U[n][k] = k<512 ? U1[n][k] : U2[n][k-512]
// ---------------------------------------------------------------------------
__global__ void bsetup_kernel(const float* __restrict__ U1, const float* __restrict__ U2,
                              _Float16* __restrict__ Bws) {
  int g = blockIdx.x * 256 + threadIdx.x;   // 65536 slots of 8 fp16
  int s  = g & 7;
  int r  = (g >> 3) & 127;
  int kt = (g >> 10) & 15;
  int nt = g >> 14;
  int n = nt * 128 + r;
  int k = kt * 64 + ((s ^ (r & 7)) << 3);
  const float* p = (k < 512) ? (U1 + (size_t)n * 1024 + k)
                             : (U2 + (size_t)n * 512 + (k - 512));
  float4 a = *(const float4*)p;
  float4 b = *(const float4*)(p + 4);
  _Float16 hv[8];
  hv[0]=(_Float16)a.x; hv[1]=(_Float16)a.y; hv[2]=(_Float16)a.z; hv[3]=(_Float16)a.w;
  hv[4]=(_Float16)b.x; hv[5]=(_Float16)b.y; hv[6]=(_Float16)b.z; hv[7]=(_Float16)b.w;
  *(uint4*)(Bws + ((size_t)g << 3)) = *(uint4*)hv;
}

// ---------------------------------------------------------------------------
// bias[b][n] = sum_h h[b][S-1][h] * U1[n][512+h]   (fp32, exact)
// ---------------------------------------------------------------------------
__global__ void bias_kernel(const float* __restrict__ hT, const float* __restrict__ U1,
                            float* __restrict__ bias) {
  const int b = blockIdx.x, t = threadIdx.x;
  const int l = t & 63, w = t >> 6;
  __shared__ float4 hl[128];
  if (t < 128) hl[t] = *(const float4*)(hT + ((size_t)b * 512 + 511) * 512 + t * 4);
  __syncthreads();
  for (int n = w; n < 512; n += 4) {
    const float4* ur = (const float4*)(U1 + (size_t)n * 1024 + 512);
    float4 u0 = ur[l],      u1 = ur[l + 64];
    float4 h0 = hl[l],      h1 = hl[l + 64];
    float s = u0.x*h0.x + u0.y*h0.y + u0.z*h0.z + u0.w*h0.w
            + u1.x*h1.x + u1.y*h1.y + u1.z*h1.z + u1.w*h1.w;
#pragma unroll
    for (int d = 1; d < 64; d <<= 1) s += __shfl_xor(s, d, 64);
    if (l == 0) bias[(size_t)b * 512 + n] = s;
  }
}

// ---------------------------------------------------------------------------
// Fused GEMM: M=65536, N=512 (4 N-blocks of 128), K=1024, BK=64.
// ---------------------------------------------------------------------------
__global__ __launch_bounds__(256, 2)
void gemm_kernel(const float* __restrict__ hT, const float* __restrict__ xT,
                 const _Float16* __restrict__ Bws, const float* __restrict__ bias,
                 const float* __restrict__ Ve, float* __restrict__ e) {
  // XCD-chunked swizzle (2048 = 8*256): 4 nt-siblings of one bm consecutive
  // on the same XCD -> A-panel L2 reuse.
  const int bid  = ((int)blockIdx.x & 7) * 256 + ((int)blockIdx.x >> 3);
  const int bm   = bid >> 2;
  const int nt   = bid & 3;
  const int row0 = bm * 128;
  const int bb   = row0 >> 9;
  const int t    = threadIdx.x;
  const int l    = t & 63;
  const int wv   = t >> 6;
  const int wm   = wv >> 1, wn = wv & 1;
  const int l15  = l & 15, lhi = l >> 4;

  __shared__ __align__(16) _Float16 Asm[2][8192];   // [128 r][8 slots x 16B]
  __shared__ __align__(16) _Float16 Bsm[2][8192];   // same geometry

  const int ar = t >> 1, ahf = t & 1;               // A-stage: row, 32-col half
  const float* aRowH = hT + (size_t)(row0 + ar) * 512 + ahf * 32;
  const float* aRowX = xT + (size_t)(row0 + ar) * 512 + ahf * 32;

  f4 areg[2][8];

  auto LOADA = [&](int buf, int k2) {               // 8x global_load_dwordx4 -> regs
    const float* p = ((k2 < 8) ? aRowH : aRowX) + (k2 & 7) * 64;
#pragma unroll
    for (int q = 0; q < 8; ++q) areg[buf][q] = *(const f4*)(p + q * 4);
  };
  auto GLOADB = [&](int c, int k2) {                // 4x global_load_lds (16B)
    const _Float16* tb = Bws + ((size_t)(nt * 16 + k2) << 13);
#pragma unroll
    for (int j = 0; j < 4; ++j)
      GLOAD16(tb + j * 2048 + wv * 512 + (l << 3), &Bsm[c][j * 2048 + wv * 512]);
  };
  auto WRITEA = [&](int c, int buf) {               // cvt fp16 + 4x ds_write_b128
#pragma unroll
    for (int j = 0; j < 4; ++j) {
      const f4 v0 = areg[buf][j * 2], v1 = areg[buf][j * 2 + 1];
      _Float16 hv[8];
      hv[0]=(_Float16)v0[0]; hv[1]=(_Float16)v0[1]; hv[2]=(_Float16)v0[2]; hv[3]=(_Float16)v0[3];
      hv[4]=(_Float16)v1[0]; hv[5]=(_Float16)v1[1]; hv[6]=(_Float16)v1[2]; hv[7]=(_Float16)v1[3];
      *(uint4*)&Asm[c][ar * 64 + ((((ahf << 2) + j) ^ (ar & 7)) << 3)] = *(uint4*)hv;
    }
  };

  f4 acc[4][4];
#pragma unroll
  for (int mf = 0; mf < 4; ++mf)
#pragma unroll
    for (int nf = 0; nf < 4; ++nf)
      acc[mf][nf] = (f4){0.f, 0.f, 0.f, 0.f};

  // Prologue: tile0 fully staged; A(1) in flight across the barrier.
  LOADA(0, 0);        // A(0) -> areg[0]
  GLOADB(0, 0);       // B(0) -> Bsm[0]
  WRITEA(0, 0);       // compiler waits A(0) [vmcnt(4)], leaves B(0) in flight
  LOADA(1, 1);        // A(1) -> areg[1]
  PIPE_BARRIER(8);    // drain B(0) (oldest 4), keep A(1); publish tile0

#pragma unroll
  for (int kt = 0; kt < 16; ++kt) {
    const int c = kt & 1;
    if (kt < 15) GLOADB(c ^ 1, kt + 1);             // B(kt+1), oldest of this iter
    if (kt < 14) LOADA(c, kt + 2);                  // A(kt+2) -> areg[c] (free: A(kt) consumed)
#pragma unroll
    for (int kk = 0; kk < 2; ++kk) {
      h8 af[4], bf[4];
#pragma unroll
      for (int mf = 0; mf < 4; ++mf) {
        const int rA = wm * 64 + mf * 16 + l15;
        af[mf] = *(const h8*)&Asm[c][rA * 64 + ((((kk << 2) + lhi) ^ (l15 & 7)) << 3)];
      }
#pragma unroll
      for (int nf = 0; nf < 4; ++nf) {
        const int rB = wn * 64 + nf * 16 + l15;
        bf[nf] = *(const h8*)&Bsm[c][rB * 64 + ((((kk << 2) + lhi) ^ (l15 & 7)) << 3)];
      }
#pragma unroll
      for (int mf = 0; mf < 4; ++mf)
#pragma unroll
        for (int nf = 0; nf < 4; ++nf)
          acc[mf][nf] = __builtin_amdgcn_mfma_f32_16x16x32_f16(af[mf], bf[nf], acc[mf][nf], 0, 0, 0);
    }
    if (kt < 15) WRITEA(c ^ 1, c ^ 1);              // write A(kt+1) into buf c^1
    if (kt < 14)       { PIPE_BARRIER(8); }         // drain B(kt+1), keep A(kt+2)
    else if (kt == 14) { PIPE_BARRIER(0); }         // nothing to keep
  }

  // Epilogue: e[row] += sum over this wave's 64 cols of tanh(u)*Ve
  float vev[4], biasv[4];
#pragma unroll
  for (int nf = 0; nf < 4; ++nf) {
    int cidx = nt * 128 + wn * 64 + nf * 16 + l15;
    vev[nf]   = Ve[cidx];
    biasv[nf] = bias[(size_t)bb * 512 + cidx];
  }
#pragma unroll
  for (int mf = 0; mf < 4; ++mf) {
#pragma unroll
    for (int j = 0; j < 4; ++j) {
      float s = 0.f;
#pragma unroll
      for (int nf = 0; nf < 4; ++nf)
        s += tanhf(acc[mf][nf][j] + biasv[nf]) * vev[nf];
#pragma unroll
      for (int m = 1; m < 16; m <<= 1) s += __shfl_xor(s, m, 64);
      if (l15 == 0) atomicAdd(&e[row0 + wm * 64 + mf * 16 + lhi * 4 + j], s);
    }
  }
}

// ---------------------------------------------------------------------------
// Softmax over S (in place: e -> alpha). One block per batch.
// ---------------------------------------------------------------------------
__global__ void softmax_kernel(float* __restrict__ e) {
  const int b = blockIdx.x, t = threadIdx.x;   // 256 threads
  float* row = e + (size_t)b * 512;
  float v0 = row[t], v1 = row[t + 256];
  float m = fmaxf(v0, v1);
#pragma unroll
  for (int d = 1; d < 64; d <<= 1) m = fmaxf(m, __shfl_xor(m, d, 64));
  __shared__ float r1[4], r2[4];
  if ((t & 63) == 0) r1[t >> 6] = m;
  __syncthreads();
  m = fmaxf(fmaxf(r1[0], r1[1]), fmaxf(r1[2], r1[3]));
  float e0 = expf(v0 - m), e1 = expf(v1 - m);
  float s = e0 + e1;
#pragma unroll
  for (int d = 1; d < 64; d <<= 1) s += __shfl_xor(s, d, 64);
  if ((t & 63) == 0) r2[t >> 6] = s;
  __syncthreads();
  s = r2[0] + r2[1] + r2[2] + r2[3];
  float inv = 1.0f / s;
  row[t]       = e0 * inv;
  row[t + 256] = e1 * inv;
}

// ---------------------------------------------------------------------------
// context[b][hd] = sum_s alpha[b][s] * h[b][s][hd]  (s split 4-way, atomic)
// ---------------------------------------------------------------------------
__global__ __launch_bounds__(512)
void ctx_kernel(const float* __restrict__ hT, const float* __restrict__ alpha,
                float* __restrict__ out) {
  const int b  = blockIdx.x >> 2;
  const int sc = blockIdx.x & 3;
  const int hd = threadIdx.x;
  __shared__ float al[128];
  if (threadIdx.x < 128) al[threadIdx.x] = alpha[(size_t)b * 512 + sc * 128 + threadIdx.x];
  __syncthreads();
  const float* hp = hT + ((size_t)b * 512 + sc * 128) * 512 + hd;
  float acc = 0.f;
#pragma unroll 4
  for (int s = 0; s < 128; ++s) acc += al[s] * hp[(size_t)s * 512];
  atomicAdd(&out[b * 512 + hd], acc);
}

// ---------------------------------------------------------------------------
extern "C" void kernel_launch(void* const* d_in, const int* in_sizes, int n_in,
                              void* d_out, int out_size, void* d_ws, size_t ws_size,
                              hipStream_t stream) {
  const float* h  = (const float*)d_in[0];
  const float* x  = (const float*)d_in[1];
  const float* Ve = (const float*)d_in[2];
  const float* U1 = (const float*)d_in[3];
  const float* U2 = (const float*)d_in[4];
  float* out = (float*)d_out;

  // ws layout: Bws fp16 tile-images 1 MB | bias f32 256 KB | e f32 256 KB
  _Float16* Bws  = (_Float16*)d_ws;
  float*    bias = (float*)((char*)d_ws + (1u << 20));
  float*    e    = (float*)((char*)d_ws + (1u << 20) + (256u << 10));
  if (ws_size < ((1u << 20) + (512u << 10))) return;

  hipMemsetAsync(e, 0, 65536 * sizeof(float), stream);
  hipMemsetAsync(d_out, 0, 65536 * sizeof(float), stream);

  bsetup_kernel<<<256, 256, 0, stream>>>(U1, U2, Bws);
  bias_kernel<<<128, 256, 0, stream>>>(h, U1, bias);
  gemm_kernel<<<2048, 256, 0, stream>>>(h, x, Bws, bias, Ve, e);
  softmax_kernel<<<128, 256, 0, stream>>>(e);
  ctx_kernel<<<512, 512, 0, stream>>>(h, e, out);
}

// Round 4
// 224.564 us; speedup vs baseline: 1.2710x; 1.2710x over previous
//
#include <hip/hip_runtime.h>
#include <cstdint>
#include <cstddef>

// Problem: B=128, S=512, H=512
//   context[b,h] = sum_s softmax_s( sum_k tanh(u[b,s,k]) Ve[k] ) * h[b,s,h]
//   u = h@U1a^T + x@U2^T + (h_last@U1b^T broadcast over s)
// R4: R3 pipeline (dbuf + counted vmcnt barrier) with COALESCED A staging
//   (16 lanes x 16B contiguous per row), A cvt'd fp16 on the write path.
//   BM=128 BN=128 BK=64, 4 waves, wave tile 64x64.

typedef _Float16 h8 __attribute__((ext_vector_type(8)));
typedef float    f4 __attribute__((ext_vector_type(4)));

#define GLOAD16(g, l)                                                          \
  __builtin_amdgcn_global_load_lds(                                            \
      (const __attribute__((address_space(1))) void*)(g),                      \
      (__attribute__((address_space(3))) void*)(l), 16, 0, 0)

// Counted barrier: drain oldest VMEM ops down to N, publish LDS, sync.
#define PIPE_BARRIER(N)                                                        \
  do {                                                                         \
    asm volatile("s_waitcnt vmcnt(" #N ") lgkmcnt(0)\n\ts_barrier" ::: "memory"); \
    __builtin_amdgcn_sched_barrier(0);                                         \
  } while (0)

// ---------------------------------------------------------------------------
// Setup: Bws = 64 tile images (nt 0..3, kt 0..15), each 128 rows x 8 slots x 16B,
// swizzle baked: image(r, s) = fp16 U[nt*128+r][kt*64 + ((s^(r&7))<<3) .. +8]
// U[n][k] = k<512 ? U1[n][k] : U2[n][k-512]
// ---------------------------------------------------------------------------
__global__ void bsetup_kernel(const float* __restrict__ U1, const float* __restrict__ U2,
                              _Float16* __restrict__ Bws) {
  int g = blockIdx.x * 256 + threadIdx.x;   // 65536 slots of 8 fp16
  int s  = g & 7;
  int r  = (g >> 3) & 127;
  int kt = (g >> 10) & 15;
  int nt = g >> 14;
  int n = nt * 128 + r;
  int k = kt * 64 + ((s ^ (r & 7)) << 3);
  const float* p = (k < 512) ? (U1 + (size_t)n * 1024 + k)
                             : (U2 + (size_t)n * 512 + (k - 512));
  float4 a = *(const float4*)p;
  float4 b = *(const float4*)(p + 4);
  _Float16 hv[8];
  hv[0]=(_Float16)a.x; hv[1]=(_Float16)a.y; hv[2]=(_Float16)a.z; hv[3]=(_Float16)a.w;
  hv[4]=(_Float16)b.x; hv[5]=(_Float16)b.y; hv[6]=(_Float16)b.z; hv[7]=(_Float16)b.w;
  *(uint4*)(Bws + ((size_t)g << 3)) = *(uint4*)hv;
}

// ---------------------------------------------------------------------------
// bias[b][n] = sum_h h[b][S-1][h] * U1[n][512+h]   (fp32, exact)
// ---------------------------------------------------------------------------
__global__ void bias_kernel(const float* __restrict__ hT, const float* __restrict__ U1,
                            float* __restrict__ bias) {
  const int b = blockIdx.x, t = threadIdx.x;
  const int l = t & 63, w = t >> 6;
  __shared__ float4 hl[128];
  if (t < 128) hl[t] = *(const float4*)(hT + ((size_t)b * 512 + 511) * 512 + t * 4);
  __syncthreads();
  for (int n = w; n < 512; n += 4) {
    const float4* ur = (const float4*)(U1 + (size_t)n * 1024 + 512);
    float4 u0 = ur[l],      u1 = ur[l + 64];
    float4 h0 = hl[l],      h1 = hl[l + 64];
    float s = u0.x*h0.x + u0.y*h0.y + u0.z*h0.z + u0.w*h0.w
            + u1.x*h1.x + u1.y*h1.y + u1.z*h1.z + u1.w*h1.w;
#pragma unroll
    for (int d = 1; d < 64; d <<= 1) s += __shfl_xor(s, d, 64);
    if (l == 0) bias[(size_t)b * 512 + n] = s;
  }
}

// ---------------------------------------------------------------------------
// Fused GEMM: M=65536, N=512 (4 N-blocks of 128), K=1024, BK=64.
// ---------------------------------------------------------------------------
__global__ __launch_bounds__(256, 2)
void gemm_kernel(const float* __restrict__ hT, const float* __restrict__ xT,
                 const _Float16* __restrict__ Bws, const float* __restrict__ bias,
                 const float* __restrict__ Ve, float* __restrict__ e) {
  // XCD-chunked swizzle (2048 = 8*256): the 4 nt-siblings of one bm are
  // consecutive on the same XCD -> A-panel L2 reuse.
  const int bid  = ((int)blockIdx.x & 7) * 256 + ((int)blockIdx.x >> 3);
  const int bm   = bid >> 2;
  const int nt   = bid & 3;
  const int row0 = bm * 128;
  const int bb   = row0 >> 9;
  const int t    = threadIdx.x;
  const int l    = t & 63;
  const int wv   = t >> 6;
  const int wm   = wv >> 1, wn = wv & 1;
  const int l15  = l & 15, lhi = l >> 4;

  __shared__ __align__(16) _Float16 Asm[2][8192];   // [128 r][8 slots x 16B]
  __shared__ __align__(16) _Float16 Bsm[2][8192];

  const int arow = t >> 4;   // 0..15 : A-stage row within 16-row group
  const int aslt = t & 15;   // 16 lanes x 16B = 256 B contiguous per row

  f4 areg[2][8];

  auto LOADA = [&](int buf, int k2) {   // 8x coalesced global_load_dwordx4
    const float* p = ((k2 < 8) ? hT : xT) + (size_t)row0 * 512 + (k2 & 7) * 64 + aslt * 4;
#pragma unroll
    for (int q = 0; q < 8; ++q)
      areg[buf][q] = *(const f4*)(p + (size_t)(q * 16 + arow) * 512);
  };
  auto GLOADB = [&](int c, int k2) {    // 4x global_load_lds (16B), image linear
    const _Float16* tb = Bws + ((size_t)(nt * 16 + k2) << 13);
#pragma unroll
    for (int j = 0; j < 4; ++j)
      GLOAD16(tb + ((j * 256 + wv * 64 + l) << 3), &Bsm[c][(j * 256 + wv * 64) << 3]);
  };
  auto WRITEA = [&](int c, int buf) {   // cvt fp16 + 8x ds_write_b64 (swizzled)
#pragma unroll
    for (int q = 0; q < 8; ++q) {
      const f4 v = areg[buf][q];
      _Float16 hv[4];
      hv[0]=(_Float16)v[0]; hv[1]=(_Float16)v[1]; hv[2]=(_Float16)v[2]; hv[3]=(_Float16)v[3];
      const int r = q * 16 + arow;
      *(uint2*)&Asm[c][r * 64 + (((aslt >> 1) ^ (r & 7)) << 3) + ((aslt & 1) << 2)] = *(uint2*)hv;
    }
  };

  f4 acc[4][4];
#pragma unroll
  for (int mf = 0; mf < 4; ++mf)
#pragma unroll
    for (int nf = 0; nf < 4; ++nf)
      acc[mf][nf] = (f4){0.f, 0.f, 0.f, 0.f};

  // Prologue: tile0 staged + published; A(1) regs in flight across barrier.
  GLOADB(0, 0);
  LOADA(0, 0);
  WRITEA(0, 0);        // compiler drains A(0) (and B(0)) here
  LOADA(1, 1);
  PIPE_BARRIER(8);     // keep A(1)'s 8 loads in flight

#pragma unroll
  for (int kt = 0; kt < 16; ++kt) {
    const int c = kt & 1;
    if (kt < 15) GLOADB(c ^ 1, kt + 1);   // 4 ops, oldest this iter
    if (kt < 14) LOADA(c, kt + 2);        // 8 ops (areg[c] free: A(kt) in LDS)
    __builtin_amdgcn_sched_barrier(0);    // pin prefetch issue before compute
#pragma unroll
    for (int kk = 0; kk < 2; ++kk) {
      h8 af[4], bf[4];
#pragma unroll
      for (int mf = 0; mf < 4; ++mf) {
        const int rA = wm * 64 + mf * 16 + l15;
        af[mf] = *(const h8*)&Asm[c][rA * 64 + ((((kk << 2) + lhi) ^ (rA & 7)) << 3)];
      }
#pragma unroll
      for (int nf = 0; nf < 4; ++nf) {
        const int rB = wn * 64 + nf * 16 + l15;
        bf[nf] = *(const h8*)&Bsm[c][rB * 64 + ((((kk << 2) + lhi) ^ (rB & 7)) << 3)];
      }
#pragma unroll
      for (int mf = 0; mf < 4; ++mf)
#pragma unroll
        for (int nf = 0; nf < 4; ++nf)
          acc[mf][nf] = __builtin_amdgcn_mfma_f32_16x16x32_f16(af[mf], bf[nf], acc[mf][nf], 0, 0, 0);
    }
    if (kt < 15) WRITEA(c ^ 1, c ^ 1);    // waits A(kt+1) only (vmcnt(12))
    if (kt < 14)       { PIPE_BARRIER(8); }   // drain B(kt+1), keep A(kt+2)
    else if (kt == 14) { PIPE_BARRIER(0); }
  }

  // Epilogue: e[row] += sum over this wave's 64 cols of tanh(u)*Ve
  float vev[4], biasv[4];
#pragma unroll
  for (int nf = 0; nf < 4; ++nf) {
    int cidx = nt * 128 + wn * 64 + nf * 16 + l15;
    vev[nf]   = Ve[cidx];
    biasv[nf] = bias[(size_t)bb * 512 + cidx];
  }
#pragma unroll
  for (int mf = 0; mf < 4; ++mf) {
#pragma unroll
    for (int j = 0; j < 4; ++j) {
      float s = 0.f;
#pragma unroll
      for (int nf = 0; nf < 4; ++nf)
        s += tanhf(acc[mf][nf][j] + biasv[nf]) * vev[nf];
#pragma unroll
      for (int m = 1; m < 16; m <<= 1) s += __shfl_xor(s, m, 64);
      if (l15 == 0) atomicAdd(&e[row0 + wm * 64 + mf * 16 + lhi * 4 + j], s);
    }
  }
}

// ---------------------------------------------------------------------------
// Softmax over S (in place: e -> alpha). One block per batch.
// ---------------------------------------------------------------------------
__global__ void softmax_kernel(float* __restrict__ e) {
  const int b = blockIdx.x, t = threadIdx.x;   // 256 threads
  float* row = e + (size_t)b * 512;
  float v0 = row[t], v1 = row[t + 256];
  float m = fmaxf(v0, v1);
#pragma unroll
  for (int d = 1; d < 64; d <<= 1) m = fmaxf(m, __shfl_xor(m, d, 64));
  __shared__ float r1[4], r2[4];
  if ((t & 63) == 0) r1[t >> 6] = m;
  __syncthreads();
  m = fmaxf(fmaxf(r1[0], r1[1]), fmaxf(r1[2], r1[3]));
  float e0 = expf(v0 - m), e1 = expf(v1 - m);
  float s = e0 + e1;
#pragma unroll
  for (int d = 1; d < 64; d <<= 1) s += __shfl_xor(s, d, 64);
  if ((t & 63) == 0) r2[t >> 6] = s;
  __syncthreads();
  s = r2[0] + r2[1] + r2[2] + r2[3];
  float inv = 1.0f / s;
  row[t]       = e0 * inv;
  row[t + 256] = e1 * inv;
}

// ---------------------------------------------------------------------------
// context[b][hd] = sum_s alpha[b][s] * h[b][s][hd]  (s split 4-way, atomic)
// ---------------------------------------------------------------------------
__global__ __launch_bounds__(512)
void ctx_kernel(const float* __restrict__ hT, const float* __restrict__ alpha,
                float* __restrict__ out) {
  const int b  = blockIdx.x >> 2;
  const int sc = blockIdx.x & 3;
  const int hd = threadIdx.x;
  __shared__ float al[128];
  if (threadIdx.x < 128) al[threadIdx.x] = alpha[(size_t)b * 512 + sc * 128 + threadIdx.x];
  __syncthreads();
  const float* hp = hT + ((size_t)b * 512 + sc * 128) * 512 + hd;
  float acc = 0.f;
#pragma unroll 4
  for (int s = 0; s < 128; ++s) acc += al[s] * hp[(size_t)s * 512];
  atomicAdd(&out[b * 512 + hd], acc);
}

// ---------------------------------------------------------------------------
extern "C" void kernel_launch(void* const* d_in, const int* in_sizes, int n_in,
                              void* d_out, int out_size, void* d_ws, size_t ws_size,
                              hipStream_t stream) {
  const float* h  = (const float*)d_in[0];
  const float* x  = (const float*)d_in[1];
  const float* Ve = (const float*)d_in[2];
  const float* U1 = (const float*)d_in[3];
  const float* U2 = (const float*)d_in[4];
  float* out = (float*)d_out;

  // ws layout: Bws fp16 tile-images 1 MB | bias f32 256 KB | e f32 256 KB
  _Float16* Bws  = (_Float16*)d_ws;
  float*    bias = (float*)((char*)d_ws + (1u << 20));
  float*    e    = (float*)((char*)d_ws + (1u << 20) + (256u << 10));
  if (ws_size < ((1u << 20) + (512u << 10))) return;

  hipMemsetAsync(e, 0, 65536 * sizeof(float), stream);
  hipMemsetAsync(d_out, 0, 65536 * sizeof(float), stream);

  bsetup_kernel<<<256, 256, 0, stream>>>(U1, U2, Bws);
  bias_kernel<<<128, 256, 0, stream>>>(h, U1, bias);
  gemm_kernel<<<2048, 256, 0, stream>>>(h, x, Bws, bias, Ve, e);
  softmax_kernel<<<128, 256, 0, stream>>>(e);
  ctx_kernel<<<512, 512, 0, stream>>>(h, e, out);
}